// Round 3
// baseline (28408.459 us; speedup 1.0000x reference)
//
#include <hip/hip_runtime.h>
#include <math.h>

// Problem constants: N=32768 X-matrices, C=128 classes, n=64.
#define N_X 32768
#define N_P 128
#define ND 64
#define MAT (ND*ND)          // 4096
#define NWAVE 4              // matrices per 256-thread block in eigen_kernel
#define BISECT_ITERS 26

typedef float v2f __attribute__((ext_vector_type(2)));

#if __has_builtin(__builtin_elementwise_fma)
__device__ __forceinline__ v2f vfma(v2f a, v2f b, v2f c) {
    return __builtin_elementwise_fma(a, b, c);
}
#else
__device__ __forceinline__ v2f vfma(v2f a, v2f b, v2f c) {
    return v2f{fmaf(a.x, b.x, c.x), fmaf(a.y, b.y, c.y)};
}
#endif

__device__ __forceinline__ float wsum(float t) {
    #pragma unroll
    for (int m = 1; m < 64; m <<= 1) t += __shfl_xor(t, m);
    return t;
}

__device__ __forceinline__ float frcp(float x) {   // fast approx 1/x (~1 ulp)
    return __builtin_amdgcn_rcpf(x);
}

__device__ __forceinline__ float guard_piv(float p) {
    return (fabsf(p) < 1e-22f) ? -1e-22f : p;
}

// Wave-local LDS fence. Every LDS buffer in eigen_kernel is per-wave and all
// cross-lane traffic is intra-wave, so no s_barrier is ever needed -- this
// orders THIS wave's ds ops without draining vmcnt (the reflector-archive
// global stores stay in flight).
__device__ __forceinline__ void lds_fence() {
    asm volatile("s_waitcnt lgkmcnt(0)" ::: "memory");
}

// ---------------------------------------------------------------------------
// Kernel 1: symmetrize A in place (tril + tril^T + diag).
// ---------------------------------------------------------------------------
__global__ __launch_bounds__(256) void symmetrize_kernel(float* __restrict__ A) {
    const int idx = blockIdx.x * 256 + threadIdx.x;   // 128*4096 total
    const int r   = (idx >> 6) & 63;
    const int col = idx & 63;
    if (col > r) A[idx] = A[(idx & ~4095) | (col << 6) | r];
}

// ---------------------------------------------------------------------------
// Kernel 2: symmetric eigendecomposition. 4 waves per 256-thread block, one
// matrix per wave (4-wave blocks dodge the ~16-workgroup/CU dispatch cap that
// 1-wave blocks hit). BARRIER-FREE: all LDS buffers are per-wave, so
// __syncthreads is replaced by wave-local lgkmcnt fences -- no vmcnt drains.
// Reflector archive lives in rows 0..61 of the matrix's own global storage
// (dead until the Phase-5 store), so LDS is 5 KB/block and occupancy is
// VGPR-bound. Register budget notes (hard-won):
//   - NO waves-per-EU hint: (64,4) in round 1 forced VGPR=64 and a 44 GB
//     spill cascade; unhinted round-2 code hit 216 VGPR from phase 4's
//     16-float4 global loads. Phase 4 below stages reflector rows through
//     LDS (coalesced 1-float/lane global load + ds_write) and reads them as
//     broadcast float4 with unroll 4 -> ~8 payload regs in flight.
//   - Phase-3 floor is rden[64]+y[64] (~135 live) -> expect ~150 VGPR,
//     3 waves/SIMD, 12 waves/CU.
// ---------------------------------------------------------------------------
__global__ __launch_bounds__(256) void eigen_kernel(float* __restrict__ X,
                                                    float* __restrict__ P,
                                                    float* __restrict__ coefs) {
    __shared__ __align__(16) float scrb[NWAVE][64];    // column dump
    __shared__ __align__(16) float vrowb[NWAVE][64];   // reflector v / row stage
    __shared__ __align__(16) float urowb[NWAVE][64];   // rank-2 vector u
    __shared__ __align__(8)  v2f  DEb[NWAVE][64];      // (d_i, e_i)
    const int wid  = threadIdx.x >> 6;
    const int lane = threadIdx.x & 63;
    const int b    = blockIdx.x * NWAVE + wid;
    float* M = (b < N_X) ? (X + (size_t)b * MAT)
                         : (P + (size_t)(b - N_X) * MAT);
    float* scr  = scrb[wid];
    float* vrow = vrowb[wid];
    float* urow = urowb[wid];
    v2f*   DE   = DEb[wid];

    // ---- load column `lane`; track own diagonal element incrementally ----
    float wcol[64];
    float dg = 0.f;
    #pragma unroll
    for (int i = 0; i < 64; ++i) {
        wcol[i] = M[i * ND + lane];
        if (i == lane) dg = wcol[i];
    }
    float ereg = 0.f;

    // ---- Phase 1: Householder tridiagonalization, steps k = 0..61 ----
    #pragma unroll 1
    for (int k = 0; k < 62; ++k) {
        // lane k dumps its current column to LDS
        if (lane == k) {
            #pragma unroll
            for (int j = 0; j < 16; ++j)
                *(float4*)(&scr[4 * j]) =
                    make_float4(wcol[4*j], wcol[4*j+1], wcol[4*j+2], wcol[4*j+3]);
        }
        lds_fence();

        const float xj = scr[lane];           // stride-1, conflict-free
        const float x0 = scr[k + 1];          // broadcast
        const float nx2 = wsum((lane > k) ? xj * xj : 0.f);
        const float normx = sqrtf(nx2);
        const float alpha = -copysignf(normx, x0);
        const float vn2   = 2.f * (nx2 - alpha * x0);
        const bool  ok    = (nx2 > 1e-40f);
        const float rvn   = ok ? rsqrtf(vn2) : 0.f;
        float vj = 0.f;
        if (lane == k + 1)      vj = (x0 - alpha) * rvn;
        else if (lane > k)      vj = xj * rvn;
        vrow[lane] = vj;
        M[k * ND + lane] = vj;                // archive reflector row (global,
                                              // fire-and-forget, coalesced)
        if (lane == k) ereg = alpha;          // e_k
        lds_fence();

        // w_j = 2 * (col_j . v): lazy broadcast float4 reads of v
        const float4* vp = (const float4*)(&vrow[0]);
        v2f acc = {0.f, 0.f};
        #pragma unroll 4
        for (int j = 0; j < 16; ++j) {
            const float4 q = vp[j];
            acc = vfma(v2f{wcol[4*j],   wcol[4*j+1]}, v2f{q.x, q.y}, acc);
            acc = vfma(v2f{wcol[4*j+2], wcol[4*j+3]}, v2f{q.z, q.w}, acc);
        }
        const float wj = 2.f * (acc.x + acc.y);
        const float K  = wsum(vj * wj);
        const float uj = wj - K * vj;
        urow[lane] = uj;
        lds_fence();

        // rank-2 update: col[i] -= v[i]*u_j + u[i]*v_j  (lazy v,u reads)
        {
            const float4* up = (const float4*)(&urow[0]);
            #pragma unroll 4
            for (int j = 0; j < 16; ++j) {
                const float4 qv = vp[j];
                const float4 qu = up[j];
                wcol[4*j+0] = fmaf(-qv.x, uj, fmaf(-qu.x, vj, wcol[4*j+0]));
                wcol[4*j+1] = fmaf(-qv.y, uj, fmaf(-qu.y, vj, wcol[4*j+1]));
                wcol[4*j+2] = fmaf(-qv.z, uj, fmaf(-qu.z, vj, wcol[4*j+2]));
                wcol[4*j+3] = fmaf(-qv.w, uj, fmaf(-qu.w, vj, wcol[4*j+3]));
            }
        }
        dg -= 2.f * uj * vj;
    }

    if (lane == 62) ereg = wcol[63];          // e_62 = A[63][62] (frozen)
    DE[lane] = v2f{dg, ereg};                 // (d_lane, e_lane)
    lds_fence();

    // ---- Phase 2: Gershgorin bounds + Sturm bisection (lane k -> lam_k) ----
    float glo = 1e30f, ghi = -1e30f;
    {
        float eprev = 0.f;
        #pragma unroll
        for (int i = 0; i < 64; ++i) {
            const v2f t = DE[i];
            const float e = (i < 63) ? fabsf(t.y) : 0.f;
            const float r = e + eprev;
            glo = fminf(glo, t.x - r);
            ghi = fmaxf(ghi, t.x + r);
            eprev = e;
        }
    }
    float lo = glo, hi = ghi;
    #pragma unroll 1
    for (int it = 0; it < BISECT_ITERS; ++it) {
        const float mid = 0.5f * (lo + hi);
        int cnt = 0;
        float p = 1.f, eprev = 0.f;
        #pragma unroll
        for (int i = 0; i < 64; ++i) {
            const v2f t = DE[i];
            const float num = eprev * eprev;
            p = (t.x - mid) - num * frcp(p);
            p = guard_piv(p);
            cnt += (p < 0.f) ? 1 : 0;
            eprev = t.y;
        }
        if (cnt <= lane) lo = mid; else hi = mid;
    }
    const float lam = 0.5f * (lo + hi);

    // ---- Phase 3: inverse iteration, tiny-pivot Thomas, 2 solves ----
    float rden[64], y[64];
    {
        // factor (reused across solves) + solve 1 with pseudo-random rhs
        float eprev;
        {
            const v2f t0 = DE[0];
            rden[0] = frcp(guard_piv(t0.x - lam));
            eprev = t0.y;
            y[0] = 0.7548f;
        }
        #pragma unroll
        for (int i = 1; i < 64; ++i) {
            const v2f ti = DE[i];
            const float m = eprev * rden[i-1];
            rden[i] = frcp(guard_piv((ti.x - lam) - m * eprev));
            const float bi = (float)(((unsigned)(i * 2654435761u)
                               ^ (unsigned)((lane + 1) * 40503u)) & 0xFFFFu)
                               * 3.0517578e-05f - 0.5f;
            y[i] = bi - m * y[i-1];
            eprev = ti.y;
        }
        y[63] *= rden[63];
        #pragma unroll
        for (int i = 62; i >= 0; --i)
            y[i] = (y[i] - DE[i].y * y[i+1]) * rden[i];

        // normalize, then solve 2 in place
        float n2 = 0.f;
        #pragma unroll
        for (int i = 0; i < 64; ++i) n2 = fmaf(y[i], y[i], n2);
        const float rn = rsqrtf(fmaxf(n2, 1e-30f));
        y[0] *= rn;
        eprev = DE[0].y;
        #pragma unroll
        for (int i = 1; i < 64; ++i) {
            const float m = eprev * rden[i-1];
            y[i] = y[i] * rn - m * y[i-1];
            eprev = DE[i].y;
        }
        y[63] *= rden[63];
        #pragma unroll
        for (int i = 62; i >= 0; --i)
            y[i] = (y[i] - DE[i].y * y[i+1]) * rden[i];
        n2 = 0.f;
        #pragma unroll
        for (int i = 0; i < 64; ++i) n2 = fmaf(y[i], y[i], n2);
        const float rn2 = rsqrtf(fmaxf(n2, 1e-30f));
        #pragma unroll
        for (int i = 0; i < 64; ++i) y[i] *= rn2;
    }

    // ---- Phase 3b: Gram-Schmidt vs lower neighbor when lambdas nearly
    // equal. No yp[64] copy: shuffle the neighbor column twice (lockstep
    // guarantees the second pass reads pre-update values). ----
    {
        const float lamprev = __shfl(lam, lane - 1);
        const bool doGS = (lane > 0) && ((lam - lamprev) < 1e-3f * fabsf(lam));
        float dot = 0.f;
        #pragma unroll
        for (int i = 0; i < 64; ++i)
            dot = fmaf(y[i], __shfl(y[i], lane - 1), dot);
        const float s = doGS ? dot : 0.f;
        float n2 = 0.f;
        #pragma unroll
        for (int i = 0; i < 64; ++i) {
            const float ypi = __shfl(y[i], lane - 1);
            y[i] = fmaf(-s, ypi, y[i]);
            n2 = fmaf(y[i], y[i], n2);
        }
        const float rn = rsqrtf(fmaxf(n2, 1e-30f));
        #pragma unroll
        for (int i = 0; i < 64; ++i) y[i] *= rn;
    }

    // ---- Phase 4: back-transform y <- Q y = H_0(...(H_61 y)). Reflector
    // row k is staged through the wave's LDS row: coalesced 1-float/lane
    // global load (L2-hot) + ds_write, then two passes of broadcast float4
    // LDS reads (unroll 4 -> ~8 payload regs in flight; keeps VGPR low). ----
    asm volatile("s_waitcnt vmcnt(0)" ::: "memory");   // archive fully written
    #pragma unroll 1
    for (int k = 61; k >= 0; --k) {
        const float gv = M[k * ND + lane];    // coalesced row read
        vrow[lane] = gv;                      // compiler inserts vmcnt wait
        lds_fence();
        const float4* vp = (const float4*)(&vrow[0]);
        v2f acc = {0.f, 0.f};
        #pragma unroll 4
        for (int j = 0; j < 16; ++j) {
            const float4 q = vp[j];
            acc = vfma(v2f{y[4*j],   y[4*j+1]}, v2f{q.x, q.y}, acc);
            acc = vfma(v2f{y[4*j+2], y[4*j+3]}, v2f{q.z, q.w}, acc);
        }
        const float s2 = 2.f * (acc.x + acc.y);
        #pragma unroll 4
        for (int j = 0; j < 16; ++j) {
            const float4 q = vp[j];
            y[4*j+0] = fmaf(-s2, q.x, y[4*j+0]);
            y[4*j+1] = fmaf(-s2, q.y, y[4*j+1]);
            y[4*j+2] = fmaf(-s2, q.z, y[4*j+2]);
            y[4*j+3] = fmaf(-s2, q.w, y[4*j+3]);
        }
        lds_fence();   // all reads of vrow issued before next k overwrites
    }

    // ---- Phase 5: store eigvec column + log(lambda) ----
    #pragma unroll
    for (int i = 0; i < 64; ++i) M[i * ND + lane] = y[i];
    coefs[(size_t)b * ND + lane] = logf(fmaxf(lam, 1e-12f));
}

// ---------------------------------------------------------------------------
// Kernel 3: recompose logm[i][j] = sum_k coef_k * W[i][k] * W[j][k].
// One matrix per 256-thread block, in place over W.
// ---------------------------------------------------------------------------
__global__ __launch_bounds__(256, 4) void recompose_kernel(float* __restrict__ X,
                                                           float* __restrict__ P,
                                                           const float* __restrict__ coefs) {
    __shared__ __align__(16) float WR[ND][68];   // WR[k][i] = W[i][k]
    __shared__ float Cf[ND];
    const int b = blockIdx.x;
    float* M = (b < N_X) ? (X + (size_t)b * MAT)
                         : (P + (size_t)(b - N_X) * MAT);
    const int tid = threadIdx.x;

    { // load + transpose: thread -> row r, 16-col segment q
        const int r = tid >> 2, q = (tid & 3) * 16;
        const float4 v0 = *(const float4*)(&M[r * ND + q + 0]);
        const float4 v1 = *(const float4*)(&M[r * ND + q + 4]);
        const float4 v2 = *(const float4*)(&M[r * ND + q + 8]);
        const float4 v3 = *(const float4*)(&M[r * ND + q + 12]);
        WR[q+ 0][r]=v0.x; WR[q+ 1][r]=v0.y; WR[q+ 2][r]=v0.z; WR[q+ 3][r]=v0.w;
        WR[q+ 4][r]=v1.x; WR[q+ 5][r]=v1.y; WR[q+ 6][r]=v1.z; WR[q+ 7][r]=v1.w;
        WR[q+ 8][r]=v2.x; WR[q+ 9][r]=v2.y; WR[q+10][r]=v2.z; WR[q+11][r]=v2.w;
        WR[q+12][r]=v3.x; WR[q+13][r]=v3.y; WR[q+14][r]=v3.z; WR[q+15][r]=v3.w;
    }
    if (tid < ND) Cf[tid] = coefs[(size_t)b * ND + tid];
    __syncthreads();

    const int tx = tid & 15, ty = tid >> 4;   // 4x4 output block per thread

    v2f a00={0,0},a01={0,0},a10={0,0},a11={0,0},
        a20={0,0},a21={0,0},a30={0,0},a31={0,0};

    #pragma unroll 4
    for (int k = 0; k < ND; ++k) {
        const v2f* row = (const v2f*)(&WR[k][0]);
        const float sk = Cf[k];
        const v2f skv = {sk, sk};
        const v2f aA = row[ty*2], aB = row[ty*2 + 1];
        const v2f b0 = row[tx*2] * skv, b1 = row[tx*2 + 1] * skv;
        const v2f ax0 = {aA.x, aA.x}, ax1 = {aA.y, aA.y};
        const v2f ax2 = {aB.x, aB.x}, ax3 = {aB.y, aB.y};
        a00 = vfma(ax0, b0, a00);  a01 = vfma(ax0, b1, a01);
        a10 = vfma(ax1, b0, a10);  a11 = vfma(ax1, b1, a11);
        a20 = vfma(ax2, b0, a20);  a21 = vfma(ax2, b1, a21);
        a30 = vfma(ax3, b0, a30);  a31 = vfma(ax3, b1, a31);
    }

    const int i0 = ty * 4, j0 = tx * 4;
    *(float4*)(&M[(size_t)(i0+0)*ND + j0]) = make_float4(a00.x,a00.y,a01.x,a01.y);
    *(float4*)(&M[(size_t)(i0+1)*ND + j0]) = make_float4(a10.x,a10.y,a11.x,a11.y);
    *(float4*)(&M[(size_t)(i0+2)*ND + j0]) = make_float4(a20.x,a20.y,a21.x,a21.y);
    *(float4*)(&M[(size_t)(i0+3)*ND + j0]) = make_float4(a30.x,a30.y,a31.x,a31.y);
}

// ---------------------------------------------------------------------------
// Kernel 4: off[c] = <logm(P_c), Asym_c>   (one wave per class)
// ---------------------------------------------------------------------------
__global__ __launch_bounds__(64) void off_kernel(const float* __restrict__ LP,
                                                 const float* __restrict__ AS,
                                                 float* __restrict__ off) {
    const int c = blockIdx.x, lane = threadIdx.x;
    const float* lp = LP + (size_t)c * MAT;
    const float* as = AS + (size_t)c * MAT;
    float t = 0.f;
    #pragma unroll 8
    for (int i = 0; i < ND; ++i)
        t = fmaf(lp[i * ND + lane], as[i * ND + lane], t);
    #pragma unroll
    for (int m = 32; m >= 1; m >>= 1) t += __shfl_xor(t, m);
    if (lane == 0) off[c] = t;
}

// ---------------------------------------------------------------------------
// Kernel 5: logits GEMM  out[n,c] = sum_k LX[n,k]*AS[c,k] - off[c]
// ---------------------------------------------------------------------------
__global__ __launch_bounds__(256) void logits_kernel(const float* __restrict__ LX,
                                                     const float* __restrict__ AS,
                                                     const float* __restrict__ off,
                                                     float* __restrict__ out) {
    __shared__ __align__(16) float LXs[32][132];
    __shared__ __align__(16) float ASs[32][132];
    const int tid = threadIdx.x;
    const int tx = tid & 15, ty = tid >> 4;
    const int nbase = blockIdx.x * 128;

    float offv[8];
    #pragma unroll
    for (int j = 0; j < 8; ++j) offv[j] = off[tx * 8 + j];

    float acc[8][8];
    #pragma unroll
    for (int i = 0; i < 8; ++i)
        #pragma unroll
        for (int j = 0; j < 8; ++j) acc[i][j] = 0.f;

    #pragma unroll 1
    for (int kc = 0; kc < MAT; kc += 32) {
        #pragma unroll
        for (int u = 0; u < 4; ++u) {
            const int f  = u * 256 + tid;
            const int r  = f >> 3;
            const int c4 = (f & 7) * 4;
            const float4 v = *(const float4*)(&LX[(size_t)(nbase + r) * MAT + kc + c4]);
            LXs[c4+0][r] = v.x; LXs[c4+1][r] = v.y; LXs[c4+2][r] = v.z; LXs[c4+3][r] = v.w;
            const float4 g = *(const float4*)(&AS[(size_t)r * MAT + kc + c4]);
            ASs[c4+0][r] = g.x; ASs[c4+1][r] = g.y; ASs[c4+2][r] = g.z; ASs[c4+3][r] = g.w;
        }
        __syncthreads();
        #pragma unroll 4
        for (int kk = 0; kk < 32; ++kk) {
            const float4 a0 = *(const float4*)(&LXs[kk][ty * 8]);
            const float4 a1 = *(const float4*)(&LXs[kk][ty * 8 + 4]);
            const float4 b0 = *(const float4*)(&ASs[kk][tx * 8]);
            const float4 b1 = *(const float4*)(&ASs[kk][tx * 8 + 4]);
            const float av[8] = {a0.x,a0.y,a0.z,a0.w,a1.x,a1.y,a1.z,a1.w};
            const float bv[8] = {b0.x,b0.y,b0.z,b0.w,b1.x,b1.y,b1.z,b1.w};
            #pragma unroll
            for (int i = 0; i < 8; ++i)
                #pragma unroll
                for (int j = 0; j < 8; ++j)
                    acc[i][j] = fmaf(av[i], bv[j], acc[i][j]);
        }
        __syncthreads();
    }

    #pragma unroll
    for (int i = 0; i < 8; ++i) {
        const int n = nbase + ty * 8 + i;
        const float4 o0 = make_float4(acc[i][0]-offv[0], acc[i][1]-offv[1],
                                      acc[i][2]-offv[2], acc[i][3]-offv[3]);
        const float4 o1 = make_float4(acc[i][4]-offv[4], acc[i][5]-offv[5],
                                      acc[i][6]-offv[6], acc[i][7]-offv[7]);
        *(float4*)(&out[(size_t)n * 128 + tx * 8])     = o0;
        *(float4*)(&out[(size_t)n * 128 + tx * 8 + 4]) = o1;
    }
}

// ---------------------------------------------------------------------------
extern "C" void kernel_launch(void* const* d_in, const int* in_sizes, int n_in,
                              void* d_out, int out_size, void* d_ws, size_t ws_size,
                              hipStream_t stream) {
    float* X   = (float*)d_in[0];
    float* P   = (float*)d_in[1];
    float* A   = (float*)d_in[2];
    float* out = (float*)d_out;
    float* off = (float*)d_ws;            // 128 floats of scratch
    // coef scratch (32896*64 floats = 8.4 MB) lives in d_out (16.8 MB):
    // written by eigen, consumed by recompose, then logits overwrites all of
    // d_out last.
    float* coefs = (float*)d_out;

    hipLaunchKernelGGL(symmetrize_kernel, dim3((N_P * MAT) / 256),   dim3(256), 0, stream, A);
    hipLaunchKernelGGL(eigen_kernel,      dim3((N_X + N_P) / NWAVE), dim3(256), 0, stream, X, P, coefs);
    hipLaunchKernelGGL(recompose_kernel,  dim3(N_X + N_P),           dim3(256), 0, stream, X, P, coefs);
    hipLaunchKernelGGL(off_kernel,        dim3(N_P),                 dim3(64),  0, stream, P, A, off);
    hipLaunchKernelGGL(logits_kernel,     dim3(N_X / 128),           dim3(256), 0, stream, X, A, off, out);
}

// Round 4
// 27747.968 us; speedup vs baseline: 1.0238x; 1.0238x over previous
//
#include <hip/hip_runtime.h>
#include <math.h>

// Problem constants: N=32768 X-matrices, C=128 classes, n=64.
#define N_X 32768
#define N_P 128
#define ND 64
#define MAT (ND*ND)          // 4096
#define NWAVE 4              // matrices per 256-thread block
#define BISECT_ITERS 26

typedef float v2f __attribute__((ext_vector_type(2)));

#if __has_builtin(__builtin_elementwise_fma)
__device__ __forceinline__ v2f vfma(v2f a, v2f b, v2f c) {
    return __builtin_elementwise_fma(a, b, c);
}
#else
__device__ __forceinline__ v2f vfma(v2f a, v2f b, v2f c) {
    return v2f{fmaf(a.x, b.x, c.x), fmaf(a.y, b.y, c.y)};
}
#endif

__device__ __forceinline__ float wsum(float t) {
    #pragma unroll
    for (int m = 1; m < 64; m <<= 1) t += __shfl_xor(t, m);
    return t;
}

__device__ __forceinline__ float frcp(float x) {   // fast approx 1/x (~1 ulp)
    return __builtin_amdgcn_rcpf(x);
}

__device__ __forceinline__ float guard_piv(float p) {
    return (fabsf(p) < 1e-22f) ? -1e-22f : p;
}

// Wave-local LDS fence (orders THIS wave's ds ops; no vmcnt drain).
__device__ __forceinline__ void lds_fence() {
    asm volatile("s_waitcnt lgkmcnt(0)" ::: "memory");
}

// ---------------------------------------------------------------------------
// Kernel 1: symmetrize A in place (tril + tril^T + diag).
// ---------------------------------------------------------------------------
__global__ __launch_bounds__(256) void symmetrize_kernel(float* __restrict__ A) {
    const int idx = blockIdx.x * 256 + threadIdx.x;   // 128*4096 total
    const int r   = (idx >> 6) & 63;
    const int col = idx & 63;
    if (col > r) A[idx] = A[(idx & ~4095) | (col << 6) | r];
}

// ---------------------------------------------------------------------------
// Kernel 2a: Householder tridiagonalization + Sturm bisection.
// 4 waves/block, one matrix per wave. __syncthreads barriers (the proven
// round-0 codegen shape -- rounds 1-3 showed that removing barriers lets the
// scheduler cross-schedule phases and balloon VGPR to 216-236 with multi-GB
// scratch spill; kernel-splitting is the fence the compiler can't move
// code across). Live set here is wcol[64]+temps -> expect ~100 VGPR.
// Outputs: reflector rows 0..61 of M (global archive), d -> row 62,
// e -> row 63, raw lambda -> coefs.
// ---------------------------------------------------------------------------
__global__ __launch_bounds__(256) void tridiag_kernel(float* __restrict__ X,
                                                      float* __restrict__ P,
                                                      float* __restrict__ coefs) {
    __shared__ __align__(16) float scrb[NWAVE][64];    // column dump
    __shared__ __align__(16) float vrowb[NWAVE][64];   // reflector v
    __shared__ __align__(16) float urowb[NWAVE][64];   // rank-2 vector u
    __shared__ __align__(8)  v2f  DEb[NWAVE][64];      // (d_i, e_i)
    const int wid  = threadIdx.x >> 6;
    const int lane = threadIdx.x & 63;
    const int b    = blockIdx.x * NWAVE + wid;
    float* M = (b < N_X) ? (X + (size_t)b * MAT)
                         : (P + (size_t)(b - N_X) * MAT);
    float* scr  = scrb[wid];
    float* vrow = vrowb[wid];
    float* urow = urowb[wid];
    v2f*   DE   = DEb[wid];

    // ---- load column `lane`; track own diagonal element incrementally ----
    float wcol[64];
    float dg = 0.f;
    #pragma unroll
    for (int i = 0; i < 64; ++i) {
        wcol[i] = M[i * ND + lane];
        if (i == lane) dg = wcol[i];
    }
    float ereg = 0.f;

    // ---- Phase 1: Householder tridiagonalization, steps k = 0..61 ----
    #pragma unroll 1
    for (int k = 0; k < 62; ++k) {
        // lane k dumps its current column to LDS
        if (lane == k) {
            #pragma unroll
            for (int j = 0; j < 16; ++j)
                *(float4*)(&scr[4 * j]) =
                    make_float4(wcol[4*j], wcol[4*j+1], wcol[4*j+2], wcol[4*j+3]);
        }
        __syncthreads();

        const float xj = scr[lane];           // stride-1, conflict-free
        const float x0 = scr[k + 1];          // broadcast
        const float nx2 = wsum((lane > k) ? xj * xj : 0.f);
        const float normx = sqrtf(nx2);
        const float alpha = -copysignf(normx, x0);
        const float vn2   = 2.f * (nx2 - alpha * x0);
        const bool  ok    = (nx2 > 1e-40f);
        const float rvn   = ok ? rsqrtf(vn2) : 0.f;
        float vj = 0.f;
        if (lane == k + 1)      vj = (x0 - alpha) * rvn;
        else if (lane > k)      vj = xj * rvn;
        vrow[lane] = vj;
        if (lane == k) ereg = alpha;          // e_k
        __syncthreads();
        // archive reflector row AFTER the barrier: the store gets a full
        // iteration of compute to retire before the next vmcnt(0) drain.
        M[k * ND + lane] = vj;

        // w_j = 2 * (col_j . v): lazy broadcast float4 reads of v
        const float4* vp = (const float4*)(&vrow[0]);
        v2f acc = {0.f, 0.f};
        #pragma unroll 4
        for (int j = 0; j < 16; ++j) {
            const float4 q = vp[j];
            acc = vfma(v2f{wcol[4*j],   wcol[4*j+1]}, v2f{q.x, q.y}, acc);
            acc = vfma(v2f{wcol[4*j+2], wcol[4*j+3]}, v2f{q.z, q.w}, acc);
        }
        const float wj = 2.f * (acc.x + acc.y);
        const float K  = wsum(vj * wj);
        const float uj = wj - K * vj;
        urow[lane] = uj;
        __syncthreads();

        // rank-2 update: col[i] -= v[i]*u_j + u[i]*v_j  (lazy v,u reads)
        {
            const float4* up = (const float4*)(&urow[0]);
            #pragma unroll 4
            for (int j = 0; j < 16; ++j) {
                const float4 qv = vp[j];
                const float4 qu = up[j];
                wcol[4*j+0] = fmaf(-qv.x, uj, fmaf(-qu.x, vj, wcol[4*j+0]));
                wcol[4*j+1] = fmaf(-qv.y, uj, fmaf(-qu.y, vj, wcol[4*j+1]));
                wcol[4*j+2] = fmaf(-qv.z, uj, fmaf(-qu.z, vj, wcol[4*j+2]));
                wcol[4*j+3] = fmaf(-qv.w, uj, fmaf(-qu.w, vj, wcol[4*j+3]));
            }
        }
        dg -= 2.f * uj * vj;
    }

    if (lane == 62) ereg = wcol[63];          // e_62 = A[63][62] (frozen)
    DE[lane] = v2f{dg, ereg};                 // (d_lane, e_lane)
    __syncthreads();

    // ---- Phase 2: Gershgorin bounds + Sturm bisection (lane k -> lam_k) ----
    float glo = 1e30f, ghi = -1e30f;
    {
        float eprev = 0.f;
        #pragma unroll
        for (int i = 0; i < 64; ++i) {
            const v2f t = DE[i];
            const float e = (i < 63) ? fabsf(t.y) : 0.f;
            const float r = e + eprev;
            glo = fminf(glo, t.x - r);
            ghi = fmaxf(ghi, t.x + r);
            eprev = e;
        }
    }
    float lo = glo, hi = ghi;
    #pragma unroll 1
    for (int it = 0; it < BISECT_ITERS; ++it) {
        const float mid = 0.5f * (lo + hi);
        int cnt = 0;
        float p = 1.f, eprev = 0.f;
        #pragma unroll
        for (int i = 0; i < 64; ++i) {
            const v2f t = DE[i];
            const float num = eprev * eprev;
            p = (t.x - mid) - num * frcp(p);
            p = guard_piv(p);
            cnt += (p < 0.f) ? 1 : 0;
            eprev = t.y;
        }
        if (cnt <= lane) lo = mid; else hi = mid;
    }
    const float lam = 0.5f * (lo + hi);

    // ---- hand off to eigvec_kernel: d -> row 62, e -> row 63, raw lam ----
    M[62 * ND + lane] = dg;
    M[63 * ND + lane] = ereg;
    coefs[(size_t)b * ND + lane] = lam;
}

// ---------------------------------------------------------------------------
// Kernel 2b: inverse iteration + back-transform + store. 4 waves/block, one
// matrix per wave. Own kernel so the Thomas-solve register floor
// (rden[64]+y[64] ~ 150 VGPR) can't interact with phase-1 scheduling.
// Reads d/e from M rows 62/63, raw lam from coefs; writes eigvec columns
// over M and log(lam) over coefs.
// ---------------------------------------------------------------------------
__global__ __launch_bounds__(256) void eigvec_kernel(float* __restrict__ X,
                                                     float* __restrict__ P,
                                                     float* __restrict__ coefs) {
    __shared__ __align__(8)  v2f  DEb[NWAVE][64];      // (d_i, e_i)
    __shared__ __align__(16) float vrowb[NWAVE][64];   // reflector row stage
    const int wid  = threadIdx.x >> 6;
    const int lane = threadIdx.x & 63;
    const int b    = blockIdx.x * NWAVE + wid;
    float* M = (b < N_X) ? (X + (size_t)b * MAT)
                         : (P + (size_t)(b - N_X) * MAT);
    v2f*   DE   = DEb[wid];
    float* vrow = vrowb[wid];

    const float dg   = M[62 * ND + lane];
    const float ereg = M[63 * ND + lane];
    const float lam  = coefs[(size_t)b * ND + lane];
    DE[lane] = v2f{dg, ereg};
    __syncthreads();

    // ---- Phase 3: inverse iteration, tiny-pivot Thomas, 2 solves ----
    float rden[64], y[64];
    {
        // factor (reused across solves) + solve 1 with pseudo-random rhs
        float eprev;
        {
            const v2f t0 = DE[0];
            rden[0] = frcp(guard_piv(t0.x - lam));
            eprev = t0.y;
            y[0] = 0.7548f;
        }
        #pragma unroll
        for (int i = 1; i < 64; ++i) {
            const v2f ti = DE[i];
            const float m = eprev * rden[i-1];
            rden[i] = frcp(guard_piv((ti.x - lam) - m * eprev));
            const float bi = (float)(((unsigned)(i * 2654435761u)
                               ^ (unsigned)((lane + 1) * 40503u)) & 0xFFFFu)
                               * 3.0517578e-05f - 0.5f;
            y[i] = bi - m * y[i-1];
            eprev = ti.y;
        }
        y[63] *= rden[63];
        #pragma unroll
        for (int i = 62; i >= 0; --i)
            y[i] = (y[i] - DE[i].y * y[i+1]) * rden[i];

        // normalize, then solve 2 in place
        float n2 = 0.f;
        #pragma unroll
        for (int i = 0; i < 64; ++i) n2 = fmaf(y[i], y[i], n2);
        const float rn = rsqrtf(fmaxf(n2, 1e-30f));
        y[0] *= rn;
        eprev = DE[0].y;
        #pragma unroll
        for (int i = 1; i < 64; ++i) {
            const float m = eprev * rden[i-1];
            y[i] = y[i] * rn - m * y[i-1];
            eprev = DE[i].y;
        }
        y[63] *= rden[63];
        #pragma unroll
        for (int i = 62; i >= 0; --i)
            y[i] = (y[i] - DE[i].y * y[i+1]) * rden[i];
        n2 = 0.f;
        #pragma unroll
        for (int i = 0; i < 64; ++i) n2 = fmaf(y[i], y[i], n2);
        const float rn2 = rsqrtf(fmaxf(n2, 1e-30f));
        #pragma unroll
        for (int i = 0; i < 64; ++i) y[i] *= rn2;
    }

    // ---- Phase 3b: Gram-Schmidt vs lower neighbor when lambdas nearly
    // equal. Shuffle the neighbor column twice (lockstep: second pass reads
    // pre-update values) -- no yp[64] copy. ----
    {
        const float lamprev = __shfl(lam, lane - 1);
        const bool doGS = (lane > 0) && ((lam - lamprev) < 1e-3f * fabsf(lam));
        float dot = 0.f;
        #pragma unroll
        for (int i = 0; i < 64; ++i)
            dot = fmaf(y[i], __shfl(y[i], lane - 1), dot);
        const float s = doGS ? dot : 0.f;
        float n2 = 0.f;
        #pragma unroll
        for (int i = 0; i < 64; ++i) {
            const float ypi = __shfl(y[i], lane - 1);
            y[i] = fmaf(-s, ypi, y[i]);
            n2 = fmaf(y[i], y[i], n2);
        }
        const float rn = rsqrtf(fmaxf(n2, 1e-30f));
        #pragma unroll
        for (int i = 0; i < 64; ++i) y[i] *= rn;
    }

    // ---- Phase 4: back-transform y <- Q y = H_0(...(H_61 y)). Reflector
    // row k staged through the wave's LDS row (coalesced 1-float/lane global
    // load + ds_write), then broadcast float4 reads, unroll 4 -> ~8 payload
    // regs in flight. lds_fence is wave-local (no inter-wave coupling). ----
    #pragma unroll 1
    for (int k = 61; k >= 0; --k) {
        const float gv = M[k * ND + lane];    // coalesced row read
        vrow[lane] = gv;                      // compiler inserts vmcnt wait
        lds_fence();
        const float4* vp = (const float4*)(&vrow[0]);
        v2f acc = {0.f, 0.f};
        #pragma unroll 4
        for (int j = 0; j < 16; ++j) {
            const float4 q = vp[j];
            acc = vfma(v2f{y[4*j],   y[4*j+1]}, v2f{q.x, q.y}, acc);
            acc = vfma(v2f{y[4*j+2], y[4*j+3]}, v2f{q.z, q.w}, acc);
        }
        const float s2 = 2.f * (acc.x + acc.y);
        #pragma unroll 4
        for (int j = 0; j < 16; ++j) {
            const float4 q = vp[j];
            y[4*j+0] = fmaf(-s2, q.x, y[4*j+0]);
            y[4*j+1] = fmaf(-s2, q.y, y[4*j+1]);
            y[4*j+2] = fmaf(-s2, q.z, y[4*j+2]);
            y[4*j+3] = fmaf(-s2, q.w, y[4*j+3]);
        }
        // next k's ds_write to vrow aliases these reads -> compiler keeps
        // order; per-wave DS in-order execution keeps HW order. No fence.
    }

    // ---- Phase 5: store eigvec column + log(lambda) ----
    #pragma unroll
    for (int i = 0; i < 64; ++i) M[i * ND + lane] = y[i];
    coefs[(size_t)b * ND + lane] = logf(fmaxf(lam, 1e-12f));
}

// ---------------------------------------------------------------------------
// Kernel 3: recompose logm[i][j] = sum_k coef_k * W[i][k] * W[j][k].
// One matrix per 256-thread block, in place over W.
// ---------------------------------------------------------------------------
__global__ __launch_bounds__(256, 4) void recompose_kernel(float* __restrict__ X,
                                                           float* __restrict__ P,
                                                           const float* __restrict__ coefs) {
    __shared__ __align__(16) float WR[ND][68];   // WR[k][i] = W[i][k]
    __shared__ float Cf[ND];
    const int b = blockIdx.x;
    float* M = (b < N_X) ? (X + (size_t)b * MAT)
                         : (P + (size_t)(b - N_X) * MAT);
    const int tid = threadIdx.x;

    { // load + transpose: thread -> row r, 16-col segment q
        const int r = tid >> 2, q = (tid & 3) * 16;
        const float4 v0 = *(const float4*)(&M[r * ND + q + 0]);
        const float4 v1 = *(const float4*)(&M[r * ND + q + 4]);
        const float4 v2 = *(const float4*)(&M[r * ND + q + 8]);
        const float4 v3 = *(const float4*)(&M[r * ND + q + 12]);
        WR[q+ 0][r]=v0.x; WR[q+ 1][r]=v0.y; WR[q+ 2][r]=v0.z; WR[q+ 3][r]=v0.w;
        WR[q+ 4][r]=v1.x; WR[q+ 5][r]=v1.y; WR[q+ 6][r]=v1.z; WR[q+ 7][r]=v1.w;
        WR[q+ 8][r]=v2.x; WR[q+ 9][r]=v2.y; WR[q+10][r]=v2.z; WR[q+11][r]=v2.w;
        WR[q+12][r]=v3.x; WR[q+13][r]=v3.y; WR[q+14][r]=v3.z; WR[q+15][r]=v3.w;
    }
    if (tid < ND) Cf[tid] = coefs[(size_t)b * ND + tid];
    __syncthreads();

    const int tx = tid & 15, ty = tid >> 4;   // 4x4 output block per thread

    v2f a00={0,0},a01={0,0},a10={0,0},a11={0,0},
        a20={0,0},a21={0,0},a30={0,0},a31={0,0};

    #pragma unroll 4
    for (int k = 0; k < ND; ++k) {
        const v2f* row = (const v2f*)(&WR[k][0]);
        const float sk = Cf[k];
        const v2f skv = {sk, sk};
        const v2f aA = row[ty*2], aB = row[ty*2 + 1];
        const v2f b0 = row[tx*2] * skv, b1 = row[tx*2 + 1] * skv;
        const v2f ax0 = {aA.x, aA.x}, ax1 = {aA.y, aA.y};
        const v2f ax2 = {aB.x, aB.x}, ax3 = {aB.y, aB.y};
        a00 = vfma(ax0, b0, a00);  a01 = vfma(ax0, b1, a01);
        a10 = vfma(ax1, b0, a10);  a11 = vfma(ax1, b1, a11);
        a20 = vfma(ax2, b0, a20);  a21 = vfma(ax2, b1, a21);
        a30 = vfma(ax3, b0, a30);  a31 = vfma(ax3, b1, a31);
    }

    const int i0 = ty * 4, j0 = tx * 4;
    *(float4*)(&M[(size_t)(i0+0)*ND + j0]) = make_float4(a00.x,a00.y,a01.x,a01.y);
    *(float4*)(&M[(size_t)(i0+1)*ND + j0]) = make_float4(a10.x,a10.y,a11.x,a11.y);
    *(float4*)(&M[(size_t)(i0+2)*ND + j0]) = make_float4(a20.x,a20.y,a21.x,a21.y);
    *(float4*)(&M[(size_t)(i0+3)*ND + j0]) = make_float4(a30.x,a30.y,a31.x,a31.y);
}

// ---------------------------------------------------------------------------
// Kernel 4: off[c] = <logm(P_c), Asym_c>   (one wave per class)
// ---------------------------------------------------------------------------
__global__ __launch_bounds__(64) void off_kernel(const float* __restrict__ LP,
                                                 const float* __restrict__ AS,
                                                 float* __restrict__ off) {
    const int c = blockIdx.x, lane = threadIdx.x;
    const float* lp = LP + (size_t)c * MAT;
    const float* as = AS + (size_t)c * MAT;
    float t = 0.f;
    #pragma unroll 8
    for (int i = 0; i < ND; ++i)
        t = fmaf(lp[i * ND + lane], as[i * ND + lane], t);
    #pragma unroll
    for (int m = 32; m >= 1; m >>= 1) t += __shfl_xor(t, m);
    if (lane == 0) off[c] = t;
}

// ---------------------------------------------------------------------------
// Kernel 5: logits GEMM  out[n,c] = sum_k LX[n,k]*AS[c,k] - off[c]
// ---------------------------------------------------------------------------
__global__ __launch_bounds__(256) void logits_kernel(const float* __restrict__ LX,
                                                     const float* __restrict__ AS,
                                                     const float* __restrict__ off,
                                                     float* __restrict__ out) {
    __shared__ __align__(16) float LXs[32][132];
    __shared__ __align__(16) float ASs[32][132];
    const int tid = threadIdx.x;
    const int tx = tid & 15, ty = tid >> 4;
    const int nbase = blockIdx.x * 128;

    float offv[8];
    #pragma unroll
    for (int j = 0; j < 8; ++j) offv[j] = off[tx * 8 + j];

    float acc[8][8];
    #pragma unroll
    for (int i = 0; i < 8; ++i)
        #pragma unroll
        for (int j = 0; j < 8; ++j) acc[i][j] = 0.f;

    #pragma unroll 1
    for (int kc = 0; kc < MAT; kc += 32) {
        #pragma unroll
        for (int u = 0; u < 4; ++u) {
            const int f  = u * 256 + tid;
            const int r  = f >> 3;
            const int c4 = (f & 7) * 4;
            const float4 v = *(const float4*)(&LX[(size_t)(nbase + r) * MAT + kc + c4]);
            LXs[c4+0][r] = v.x; LXs[c4+1][r] = v.y; LXs[c4+2][r] = v.z; LXs[c4+3][r] = v.w;
            const float4 g = *(const float4*)(&AS[(size_t)r * MAT + kc + c4]);
            ASs[c4+0][r] = g.x; ASs[c4+1][r] = g.y; ASs[c4+2][r] = g.z; ASs[c4+3][r] = g.w;
        }
        __syncthreads();
        #pragma unroll 4
        for (int kk = 0; kk < 32; ++kk) {
            const float4 a0 = *(const float4*)(&LXs[kk][ty * 8]);
            const float4 a1 = *(const float4*)(&LXs[kk][ty * 8 + 4]);
            const float4 b0 = *(const float4*)(&ASs[kk][tx * 8]);
            const float4 b1 = *(const float4*)(&ASs[kk][tx * 8 + 4]);
            const float av[8] = {a0.x,a0.y,a0.z,a0.w,a1.x,a1.y,a1.z,a1.w};
            const float bv[8] = {b0.x,b0.y,b0.z,b0.w,b1.x,b1.y,b1.z,b1.w};
            #pragma unroll
            for (int i = 0; i < 8; ++i)
                #pragma unroll
                for (int j = 0; j < 8; ++j)
                    acc[i][j] = fmaf(av[i], bv[j], acc[i][j]);
        }
        __syncthreads();
    }

    #pragma unroll
    for (int i = 0; i < 8; ++i) {
        const int n = nbase + ty * 8 + i;
        const float4 o0 = make_float4(acc[i][0]-offv[0], acc[i][1]-offv[1],
                                      acc[i][2]-offv[2], acc[i][3]-offv[3]);
        const float4 o1 = make_float4(acc[i][4]-offv[4], acc[i][5]-offv[5],
                                      acc[i][6]-offv[6], acc[i][7]-offv[7]);
        *(float4*)(&out[(size_t)n * 128 + tx * 8])     = o0;
        *(float4*)(&out[(size_t)n * 128 + tx * 8 + 4]) = o1;
    }
}

// ---------------------------------------------------------------------------
extern "C" void kernel_launch(void* const* d_in, const int* in_sizes, int n_in,
                              void* d_out, int out_size, void* d_ws, size_t ws_size,
                              hipStream_t stream) {
    float* X   = (float*)d_in[0];
    float* P   = (float*)d_in[1];
    float* A   = (float*)d_in[2];
    float* out = (float*)d_out;
    float* off = (float*)d_ws;            // 128 floats of scratch
    // coef scratch (32896*64 floats = 8.4 MB) lives in d_out (16.8 MB):
    // raw lam written by tridiag, read+overwritten (log) by eigvec, consumed
    // by recompose, then logits overwrites all of d_out last.
    float* coefs = (float*)d_out;

    hipLaunchKernelGGL(symmetrize_kernel, dim3((N_P * MAT) / 256),   dim3(256), 0, stream, A);
    hipLaunchKernelGGL(tridiag_kernel,    dim3((N_X + N_P) / NWAVE), dim3(256), 0, stream, X, P, coefs);
    hipLaunchKernelGGL(eigvec_kernel,     dim3((N_X + N_P) / NWAVE), dim3(256), 0, stream, X, P, coefs);
    hipLaunchKernelGGL(recompose_kernel,  dim3(N_X + N_P),           dim3(256), 0, stream, X, P, coefs);
    hipLaunchKernelGGL(off_kernel,        dim3(N_P),                 dim3(64),  0, stream, P, A, off);
    hipLaunchKernelGGL(logits_kernel,     dim3(N_X / 128),           dim3(256), 0, stream, X, A, off, out);
}

// Round 5
// 5609.155 us; speedup vs baseline: 5.0647x; 4.9469x over previous
//
#include <hip/hip_runtime.h>
#include <math.h>

// Problem constants: N=32768 X-matrices, C=128 classes, n=64.
#define N_X 32768
#define N_P 128
#define ND 64
#define MAT (ND*ND)          // 4096
#define NWAVE 4              // matrices per 256-thread block
#define BISECT_ITERS 26

typedef float v2f __attribute__((ext_vector_type(2)));

#if __has_builtin(__builtin_elementwise_fma)
__device__ __forceinline__ v2f vfma(v2f a, v2f b, v2f c) {
    return __builtin_elementwise_fma(a, b, c);
}
#else
__device__ __forceinline__ v2f vfma(v2f a, v2f b, v2f c) {
    return v2f{fmaf(a.x, b.x, c.x), fmaf(a.y, b.y, c.y)};
}
#endif

__device__ __forceinline__ float wsum(float t) {
    #pragma unroll
    for (int m = 1; m < 64; m <<= 1) t += __shfl_xor(t, m);
    return t;
}

__device__ __forceinline__ float frcp(float x) {   // fast approx 1/x (~1 ulp)
    return __builtin_amdgcn_rcpf(x);
}

__device__ __forceinline__ float guard_piv(float p) {
    return (fabsf(p) < 1e-22f) ? -1e-22f : p;
}

// Wave-local LDS fence (orders THIS wave's ds ops; no vmcnt drain).
__device__ __forceinline__ void lds_fence() {
    asm volatile("s_waitcnt lgkmcnt(0)" ::: "memory");
}

// RULE LEARNED (rounds 2-4): every loop that indexes a per-lane array
// (wcol[], y[], rden[]) MUST be fully unrolled -- "#pragma unroll 4" leaves
// a runtime index, which forces the array into scratch memory (10+ GB of
// scratch traffic, 5x regression). Full static unroll keeps them in VGPRs
// (round 0 measured a clean 128-VGPR kernel this way).

// ---------------------------------------------------------------------------
// Kernel 1: symmetrize A in place (tril + tril^T + diag).
// ---------------------------------------------------------------------------
__global__ __launch_bounds__(256) void symmetrize_kernel(float* __restrict__ A) {
    const int idx = blockIdx.x * 256 + threadIdx.x;   // 128*4096 total
    const int r   = (idx >> 6) & 63;
    const int col = idx & 63;
    if (col > r) A[idx] = A[(idx & ~4095) | (col << 6) | r];
}

// ---------------------------------------------------------------------------
// Kernel 2a: Householder tridiagonalization + Sturm bisection.
// 4 waves/block, one matrix per wave, __syncthreads barriers (round-0's
// proven codegen shape: 128 VGPR, no spill). The only change vs round 0:
// the reflector archive goes to rows 0..61 of M in GLOBAL (dead storage
// until eigvec_kernel overwrites M), so LDS drops 64 KB -> 5 KB and
// occupancy is VGPR-bound (~128 -> 4 waves/SIMD, 4 blocks/CU).
// Outputs: reflectors in M rows 0..61, d -> row 62, e -> row 63,
// raw lambda -> coefs.
// ---------------------------------------------------------------------------
__global__ __launch_bounds__(256) void tridiag_kernel(float* __restrict__ X,
                                                      float* __restrict__ P,
                                                      float* __restrict__ coefs) {
    __shared__ __align__(16) float scrb[NWAVE][64];    // column dump
    __shared__ __align__(16) float vrowb[NWAVE][64];   // reflector v
    __shared__ __align__(16) float urowb[NWAVE][64];   // rank-2 vector u
    __shared__ __align__(8)  v2f  DEb[NWAVE][64];      // (d_i, e_i)
    const int wid  = threadIdx.x >> 6;
    const int lane = threadIdx.x & 63;
    const int b    = blockIdx.x * NWAVE + wid;
    float* M = (b < N_X) ? (X + (size_t)b * MAT)
                         : (P + (size_t)(b - N_X) * MAT);
    float* scr  = scrb[wid];
    float* vrow = vrowb[wid];
    float* urow = urowb[wid];
    v2f*   DE   = DEb[wid];

    // ---- load column `lane`; track own diagonal element incrementally ----
    float wcol[64];
    float dg = 0.f;
    #pragma unroll
    for (int i = 0; i < 64; ++i) {
        wcol[i] = M[i * ND + lane];
        if (i == lane) dg = wcol[i];
    }
    float ereg = 0.f;

    // ---- Phase 1: Householder tridiagonalization, steps k = 0..61 ----
    #pragma unroll 1
    for (int k = 0; k < 62; ++k) {
        // lane k dumps its current column to LDS
        if (lane == k) {
            #pragma unroll
            for (int j = 0; j < 16; ++j)
                *(float4*)(&scr[4 * j]) =
                    make_float4(wcol[4*j], wcol[4*j+1], wcol[4*j+2], wcol[4*j+3]);
        }
        __syncthreads();

        const float xj = scr[lane];           // stride-1, conflict-free
        const float x0 = scr[k + 1];          // broadcast
        const float nx2 = wsum((lane > k) ? xj * xj : 0.f);
        const float normx = sqrtf(nx2);
        const float alpha = -copysignf(normx, x0);
        const float vn2   = 2.f * (nx2 - alpha * x0);
        const bool  ok    = (nx2 > 1e-40f);
        const float rvn   = ok ? rsqrtf(vn2) : 0.f;
        float vj = 0.f;
        if (lane == k + 1)      vj = (x0 - alpha) * rvn;
        else if (lane > k)      vj = xj * rvn;
        vrow[lane] = vj;                      // archive in LDS for this step
        if (lane == k) ereg = alpha;          // e_k
        __syncthreads();
        // global archive store AFTER the barrier: the dot+wsum below covers
        // its latency before the next barrier's vmcnt(0) drain.
        M[k * ND + lane] = vj;

        // read v into registers (broadcast b128 reads, FULL unroll)
        v2f vv[32];
        {
            const float4* vp = (const float4*)(&vrow[0]);
            #pragma unroll
            for (int j = 0; j < 16; ++j) {
                const float4 q = vp[j];
                vv[2*j]   = v2f{q.x, q.y};
                vv[2*j+1] = v2f{q.z, q.w};
            }
        }
        // w_j = 2 * (col_j . v)   (local dot)
        v2f acc = {0.f, 0.f};
        #pragma unroll
        for (int j = 0; j < 32; ++j)
            acc = vfma(v2f{wcol[2*j], wcol[2*j+1]}, vv[j], acc);
        const float wj = 2.f * (acc.x + acc.y);
        const float K  = wsum(vj * wj);
        const float uj = wj - K * vj;
        urow[lane] = uj;
        __syncthreads();

        // read u, rank-2 update: col_j -= v*u_j + u*v_j   (FULL unroll)
        {
            const float4* up = (const float4*)(&urow[0]);
            const v2f vjv = {vj, vj}, ujv = {uj, uj};
            #pragma unroll
            for (int j = 0; j < 16; ++j) {
                const float4 q = up[j];
                v2f u0 = {q.x, q.y}, u1 = {q.z, q.w};
                v2f w0 = {wcol[4*j],   wcol[4*j+1]};
                v2f w1 = {wcol[4*j+2], wcol[4*j+3]};
                w0 = vfma(-vv[2*j],   ujv, vfma(-u0, vjv, w0));
                w1 = vfma(-vv[2*j+1], ujv, vfma(-u1, vjv, w1));
                wcol[4*j]   = w0.x; wcol[4*j+1] = w0.y;
                wcol[4*j+2] = w1.x; wcol[4*j+3] = w1.y;
            }
        }
        dg -= 2.f * uj * vj;
    }

    if (lane == 62) ereg = wcol[63];          // e_62 = A[63][62] (frozen)
    DE[lane] = v2f{dg, ereg};                 // (d_lane, e_lane)
    __syncthreads();

    // ---- Phase 2: Gershgorin bounds + Sturm bisection (lane k -> lam_k) ----
    float glo = 1e30f, ghi = -1e30f;
    {
        float eprev = 0.f;
        #pragma unroll
        for (int i = 0; i < 64; ++i) {
            const v2f t = DE[i];
            const float e = (i < 63) ? fabsf(t.y) : 0.f;
            const float r = e + eprev;
            glo = fminf(glo, t.x - r);
            ghi = fmaxf(ghi, t.x + r);
            eprev = e;
        }
    }
    float lo = glo, hi = ghi;
    #pragma unroll 1
    for (int it = 0; it < BISECT_ITERS; ++it) {
        const float mid = 0.5f * (lo + hi);
        int cnt = 0;
        float p = 1.f, eprev = 0.f;
        #pragma unroll
        for (int i = 0; i < 64; ++i) {
            const v2f t = DE[i];
            const float num = eprev * eprev;
            p = (t.x - mid) - num * frcp(p);
            p = guard_piv(p);
            cnt += (p < 0.f) ? 1 : 0;
            eprev = t.y;
        }
        if (cnt <= lane) lo = mid; else hi = mid;
    }
    const float lam = 0.5f * (lo + hi);

    // ---- hand off to eigvec_kernel: d -> row 62, e -> row 63, raw lam ----
    M[62 * ND + lane] = dg;
    M[63 * ND + lane] = ereg;
    coefs[(size_t)b * ND + lane] = lam;
}

// ---------------------------------------------------------------------------
// Kernel 2b: inverse iteration + back-transform + store. 4 waves/block, one
// matrix per wave. Own kernel so the Thomas-solve register floor
// (rden[64]+y[64] ~ 150 live) can't interact with phase-1 scheduling.
// ALL array-indexing loops fully unrolled (rule above). Phase 4 reads the
// reflector fragments directly from the LDS row (no vv copy) so the VGPR
// peak stays at phase-3's floor.
// ---------------------------------------------------------------------------
__global__ __launch_bounds__(256) void eigvec_kernel(float* __restrict__ X,
                                                     float* __restrict__ P,
                                                     float* __restrict__ coefs) {
    __shared__ __align__(8)  v2f  DEb[NWAVE][64];      // (d_i, e_i)
    __shared__ __align__(16) float vrowb[NWAVE][64];   // reflector row stage
    const int wid  = threadIdx.x >> 6;
    const int lane = threadIdx.x & 63;
    const int b    = blockIdx.x * NWAVE + wid;
    float* M = (b < N_X) ? (X + (size_t)b * MAT)
                         : (P + (size_t)(b - N_X) * MAT);
    v2f*   DE   = DEb[wid];
    float* vrow = vrowb[wid];

    const float dg   = M[62 * ND + lane];
    const float ereg = M[63 * ND + lane];
    const float lam  = coefs[(size_t)b * ND + lane];
    DE[lane] = v2f{dg, ereg};
    __syncthreads();

    // ---- Phase 3: inverse iteration, tiny-pivot Thomas, 2 solves ----
    float rden[64], y[64];
    {
        // factor (reused across solves) + solve 1 with pseudo-random rhs
        float eprev;
        {
            const v2f t0 = DE[0];
            rden[0] = frcp(guard_piv(t0.x - lam));
            eprev = t0.y;
            y[0] = 0.7548f;
        }
        #pragma unroll
        for (int i = 1; i < 64; ++i) {
            const v2f ti = DE[i];
            const float m = eprev * rden[i-1];
            rden[i] = frcp(guard_piv((ti.x - lam) - m * eprev));
            const float bi = (float)(((unsigned)(i * 2654435761u)
                               ^ (unsigned)((lane + 1) * 40503u)) & 0xFFFFu)
                               * 3.0517578e-05f - 0.5f;
            y[i] = bi - m * y[i-1];
            eprev = ti.y;
        }
        y[63] *= rden[63];
        #pragma unroll
        for (int i = 62; i >= 0; --i)
            y[i] = (y[i] - DE[i].y * y[i+1]) * rden[i];

        // normalize, then solve 2 in place
        float n2 = 0.f;
        #pragma unroll
        for (int i = 0; i < 64; ++i) n2 = fmaf(y[i], y[i], n2);
        const float rn = rsqrtf(fmaxf(n2, 1e-30f));
        y[0] *= rn;
        eprev = DE[0].y;
        #pragma unroll
        for (int i = 1; i < 64; ++i) {
            const float m = eprev * rden[i-1];
            y[i] = y[i] * rn - m * y[i-1];
            eprev = DE[i].y;
        }
        y[63] *= rden[63];
        #pragma unroll
        for (int i = 62; i >= 0; --i)
            y[i] = (y[i] - DE[i].y * y[i+1]) * rden[i];
        n2 = 0.f;
        #pragma unroll
        for (int i = 0; i < 64; ++i) n2 = fmaf(y[i], y[i], n2);
        const float rn2 = rsqrtf(fmaxf(n2, 1e-30f));
        #pragma unroll
        for (int i = 0; i < 64; ++i) y[i] *= rn2;
    }

    // ---- Phase 3b: Gram-Schmidt vs lower neighbor when lambdas nearly
    // equal. Shuffle the neighbor column twice (lockstep: second pass reads
    // pre-update values) -- no yp[64] copy. ----
    {
        const float lamprev = __shfl(lam, lane - 1);
        const bool doGS = (lane > 0) && ((lam - lamprev) < 1e-3f * fabsf(lam));
        float dot = 0.f;
        #pragma unroll
        for (int i = 0; i < 64; ++i)
            dot = fmaf(y[i], __shfl(y[i], lane - 1), dot);
        const float s = doGS ? dot : 0.f;
        float n2 = 0.f;
        #pragma unroll
        for (int i = 0; i < 64; ++i) {
            const float ypi = __shfl(y[i], lane - 1);
            y[i] = fmaf(-s, ypi, y[i]);
            n2 = fmaf(y[i], y[i], n2);
        }
        const float rn = rsqrtf(fmaxf(n2, 1e-30f));
        #pragma unroll
        for (int i = 0; i < 64; ++i) y[i] *= rn;
    }

    // ---- Phase 4: back-transform y <- Q y = H_0(...(H_61 y)). Reflector
    // row k staged through the wave's LDS row (coalesced 1-float/lane global
    // load + ds_write), then broadcast float4 LDS reads, FULL unroll so y[]
    // stays in registers. lds_fence is wave-local (no inter-wave coupling);
    // per-wave in-order DS keeps the next ds_write after this step's reads.
    #pragma unroll 1
    for (int k = 61; k >= 0; --k) {
        const float gv = M[k * ND + lane];    // coalesced row read
        vrow[lane] = gv;                      // compiler inserts vmcnt wait
        lds_fence();
        const float4* vp = (const float4*)(&vrow[0]);
        v2f acc = {0.f, 0.f};
        #pragma unroll
        for (int j = 0; j < 16; ++j) {
            const float4 q = vp[j];
            acc = vfma(v2f{y[4*j],   y[4*j+1]}, v2f{q.x, q.y}, acc);
            acc = vfma(v2f{y[4*j+2], y[4*j+3]}, v2f{q.z, q.w}, acc);
        }
        const float s2 = 2.f * (acc.x + acc.y);
        #pragma unroll
        for (int j = 0; j < 16; ++j) {
            const float4 q = vp[j];
            y[4*j+0] = fmaf(-s2, q.x, y[4*j+0]);
            y[4*j+1] = fmaf(-s2, q.y, y[4*j+1]);
            y[4*j+2] = fmaf(-s2, q.z, y[4*j+2]);
            y[4*j+3] = fmaf(-s2, q.w, y[4*j+3]);
        }
    }

    // ---- Phase 5: store eigvec column + log(lambda) ----
    #pragma unroll
    for (int i = 0; i < 64; ++i) M[i * ND + lane] = y[i];
    coefs[(size_t)b * ND + lane] = logf(fmaxf(lam, 1e-12f));
}

// ---------------------------------------------------------------------------
// Kernel 3: recompose logm[i][j] = sum_k coef_k * W[i][k] * W[j][k].
// One matrix per 256-thread block, in place over W.
// ---------------------------------------------------------------------------
__global__ __launch_bounds__(256, 4) void recompose_kernel(float* __restrict__ X,
                                                           float* __restrict__ P,
                                                           const float* __restrict__ coefs) {
    __shared__ __align__(16) float WR[ND][68];   // WR[k][i] = W[i][k]
    __shared__ float Cf[ND];
    const int b = blockIdx.x;
    float* M = (b < N_X) ? (X + (size_t)b * MAT)
                         : (P + (size_t)(b - N_X) * MAT);
    const int tid = threadIdx.x;

    { // load + transpose: thread -> row r, 16-col segment q
        const int r = tid >> 2, q = (tid & 3) * 16;
        const float4 v0 = *(const float4*)(&M[r * ND + q + 0]);
        const float4 v1 = *(const float4*)(&M[r * ND + q + 4]);
        const float4 v2 = *(const float4*)(&M[r * ND + q + 8]);
        const float4 v3 = *(const float4*)(&M[r * ND + q + 12]);
        WR[q+ 0][r]=v0.x; WR[q+ 1][r]=v0.y; WR[q+ 2][r]=v0.z; WR[q+ 3][r]=v0.w;
        WR[q+ 4][r]=v1.x; WR[q+ 5][r]=v1.y; WR[q+ 6][r]=v1.z; WR[q+ 7][r]=v1.w;
        WR[q+ 8][r]=v2.x; WR[q+ 9][r]=v2.y; WR[q+10][r]=v2.z; WR[q+11][r]=v2.w;
        WR[q+12][r]=v3.x; WR[q+13][r]=v3.y; WR[q+14][r]=v3.z; WR[q+15][r]=v3.w;
    }
    if (tid < ND) Cf[tid] = coefs[(size_t)b * ND + tid];
    __syncthreads();

    const int tx = tid & 15, ty = tid >> 4;   // 4x4 output block per thread

    v2f a00={0,0},a01={0,0},a10={0,0},a11={0,0},
        a20={0,0},a21={0,0},a30={0,0},a31={0,0};

    #pragma unroll 4
    for (int k = 0; k < ND; ++k) {
        const v2f* row = (const v2f*)(&WR[k][0]);
        const float sk = Cf[k];
        const v2f skv = {sk, sk};
        const v2f aA = row[ty*2], aB = row[ty*2 + 1];
        const v2f b0 = row[tx*2] * skv, b1 = row[tx*2 + 1] * skv;
        const v2f ax0 = {aA.x, aA.x}, ax1 = {aA.y, aA.y};
        const v2f ax2 = {aB.x, aB.x}, ax3 = {aB.y, aB.y};
        a00 = vfma(ax0, b0, a00);  a01 = vfma(ax0, b1, a01);
        a10 = vfma(ax1, b0, a10);  a11 = vfma(ax1, b1, a11);
        a20 = vfma(ax2, b0, a20);  a21 = vfma(ax2, b1, a21);
        a30 = vfma(ax3, b0, a30);  a31 = vfma(ax3, b1, a31);
    }

    const int i0 = ty * 4, j0 = tx * 4;
    *(float4*)(&M[(size_t)(i0+0)*ND + j0]) = make_float4(a00.x,a00.y,a01.x,a01.y);
    *(float4*)(&M[(size_t)(i0+1)*ND + j0]) = make_float4(a10.x,a10.y,a11.x,a11.y);
    *(float4*)(&M[(size_t)(i0+2)*ND + j0]) = make_float4(a20.x,a20.y,a21.x,a21.y);
    *(float4*)(&M[(size_t)(i0+3)*ND + j0]) = make_float4(a30.x,a30.y,a31.x,a31.y);
}

// ---------------------------------------------------------------------------
// Kernel 4: off[c] = <logm(P_c), Asym_c>   (one wave per class)
// ---------------------------------------------------------------------------
__global__ __launch_bounds__(64) void off_kernel(const float* __restrict__ LP,
                                                 const float* __restrict__ AS,
                                                 float* __restrict__ off) {
    const int c = blockIdx.x, lane = threadIdx.x;
    const float* lp = LP + (size_t)c * MAT;
    const float* as = AS + (size_t)c * MAT;
    float t = 0.f;
    #pragma unroll 8
    for (int i = 0; i < ND; ++i)
        t = fmaf(lp[i * ND + lane], as[i * ND + lane], t);
    #pragma unroll
    for (int m = 32; m >= 1; m >>= 1) t += __shfl_xor(t, m);
    if (lane == 0) off[c] = t;
}

// ---------------------------------------------------------------------------
// Kernel 5: logits GEMM  out[n,c] = sum_k LX[n,k]*AS[c,k] - off[c]
// ---------------------------------------------------------------------------
__global__ __launch_bounds__(256) void logits_kernel(const float* __restrict__ LX,
                                                     const float* __restrict__ AS,
                                                     const float* __restrict__ off,
                                                     float* __restrict__ out) {
    __shared__ __align__(16) float LXs[32][132];
    __shared__ __align__(16) float ASs[32][132];
    const int tid = threadIdx.x;
    const int tx = tid & 15, ty = tid >> 4;
    const int nbase = blockIdx.x * 128;

    float offv[8];
    #pragma unroll
    for (int j = 0; j < 8; ++j) offv[j] = off[tx * 8 + j];

    float acc[8][8];
    #pragma unroll
    for (int i = 0; i < 8; ++i)
        #pragma unroll
        for (int j = 0; j < 8; ++j) acc[i][j] = 0.f;

    #pragma unroll 1
    for (int kc = 0; kc < MAT; kc += 32) {
        #pragma unroll
        for (int u = 0; u < 4; ++u) {
            const int f  = u * 256 + tid;
            const int r  = f >> 3;
            const int c4 = (f & 7) * 4;
            const float4 v = *(const float4*)(&LX[(size_t)(nbase + r) * MAT + kc + c4]);
            LXs[c4+0][r] = v.x; LXs[c4+1][r] = v.y; LXs[c4+2][r] = v.z; LXs[c4+3][r] = v.w;
            const float4 g = *(const float4*)(&AS[(size_t)r * MAT + kc + c4]);
            ASs[c4+0][r] = g.x; ASs[c4+1][r] = g.y; ASs[c4+2][r] = g.z; ASs[c4+3][r] = g.w;
        }
        __syncthreads();
        #pragma unroll 4
        for (int kk = 0; kk < 32; ++kk) {
            const float4 a0 = *(const float4*)(&LXs[kk][ty * 8]);
            const float4 a1 = *(const float4*)(&LXs[kk][ty * 8 + 4]);
            const float4 b0 = *(const float4*)(&ASs[kk][tx * 8]);
            const float4 b1 = *(const float4*)(&ASs[kk][tx * 8 + 4]);
            const float av[8] = {a0.x,a0.y,a0.z,a0.w,a1.x,a1.y,a1.z,a1.w};
            const float bv[8] = {b0.x,b0.y,b0.z,b0.w,b1.x,b1.y,b1.z,b1.w};
            #pragma unroll
            for (int i = 0; i < 8; ++i)
                #pragma unroll
                for (int j = 0; j < 8; ++j)
                    acc[i][j] = fmaf(av[i], bv[j], acc[i][j]);
        }
        __syncthreads();
    }

    #pragma unroll
    for (int i = 0; i < 8; ++i) {
        const int n = nbase + ty * 8 + i;
        const float4 o0 = make_float4(acc[i][0]-offv[0], acc[i][1]-offv[1],
                                      acc[i][2]-offv[2], acc[i][3]-offv[3]);
        const float4 o1 = make_float4(acc[i][4]-offv[4], acc[i][5]-offv[5],
                                      acc[i][6]-offv[6], acc[i][7]-offv[7]);
        *(float4*)(&out[(size_t)n * 128 + tx * 8])     = o0;
        *(float4*)(&out[(size_t)n * 128 + tx * 8 + 4]) = o1;
    }
}

// ---------------------------------------------------------------------------
extern "C" void kernel_launch(void* const* d_in, const int* in_sizes, int n_in,
                              void* d_out, int out_size, void* d_ws, size_t ws_size,
                              hipStream_t stream) {
    float* X   = (float*)d_in[0];
    float* P   = (float*)d_in[1];
    float* A   = (float*)d_in[2];
    float* out = (float*)d_out;
    float* off = (float*)d_ws;            // 128 floats of scratch
    // coef scratch (32896*64 floats = 8.4 MB) lives in d_out (16.8 MB):
    // raw lam written by tridiag, read+overwritten (log) by eigvec, consumed
    // by recompose, then logits overwrites all of d_out last.
    float* coefs = (float*)d_out;

    hipLaunchKernelGGL(symmetrize_kernel, dim3((N_P * MAT) / 256),   dim3(256), 0, stream, A);
    hipLaunchKernelGGL(tridiag_kernel,    dim3((N_X + N_P) / NWAVE), dim3(256), 0, stream, X, P, coefs);
    hipLaunchKernelGGL(eigvec_kernel,     dim3((N_X + N_P) / NWAVE), dim3(256), 0, stream, X, P, coefs);
    hipLaunchKernelGGL(recompose_kernel,  dim3(N_X + N_P),           dim3(256), 0, stream, X, P, coefs);
    hipLaunchKernelGGL(off_kernel,        dim3(N_P),                 dim3(64),  0, stream, P, A, off);
    hipLaunchKernelGGL(logits_kernel,     dim3(N_X / 128),           dim3(256), 0, stream, X, A, off, out);
}

// Round 6
// 4591.570 us; speedup vs baseline: 6.1871x; 1.2216x over previous
//
#include <hip/hip_runtime.h>
#include <math.h>

// Problem constants: N=32768 X-matrices, C=128 classes, n=64.
#define N_X 32768
#define N_P 128
#define ND 64
#define MAT (ND*ND)          // 4096
#define NWAVE 4              // matrices per 256-thread block (eigvec only)
#define BISECT_ITERS 26

typedef float v2f __attribute__((ext_vector_type(2)));

#if __has_builtin(__builtin_elementwise_fma)
__device__ __forceinline__ v2f vfma(v2f a, v2f b, v2f c) {
    return __builtin_elementwise_fma(a, b, c);
}
#else
__device__ __forceinline__ v2f vfma(v2f a, v2f b, v2f c) {
    return v2f{fmaf(a.x, b.x, c.x), fmaf(a.y, b.y, c.y)};
}
#endif

__device__ __forceinline__ float wsum(float t) {
    #pragma unroll
    for (int m = 1; m < 64; m <<= 1) t += __shfl_xor(t, m);
    return t;
}

__device__ __forceinline__ float frcp(float x) {   // fast approx 1/x (~1 ulp)
    return __builtin_amdgcn_rcpf(x);
}

__device__ __forceinline__ float guard_piv(float p) {
    return (fabsf(p) < 1e-22f) ? -1e-22f : p;
}

// Wave-local sync point: orders THIS wave's ds ops (lgkmcnt(0)) and pins the
// compiler's scheduling regions (sched_barrier(0)), WITHOUT s_barrier's
// 4-wave coupling and WITHOUT the vmcnt(0) drain that __syncthreads emits
// (which force-drained the fire-and-forget reflector stores every step).
// Rounds 1-3 showed lgkmcnt alone is numerically correct but lets the
// scheduler cross-schedule phases and balloon VGPR 88 -> 216+; the
// sched_barrier is the compile-time fence that prevents that.
__device__ __forceinline__ void wave_sync() {
    asm volatile("s_waitcnt lgkmcnt(0)" ::: "memory");
    __builtin_amdgcn_sched_barrier(0);
}

// RULE (rounds 2-4): every loop indexing a per-lane array (wcol[], y[],
// rden[]) MUST be fully unrolled -- a partial "#pragma unroll 4" leaves a
// runtime index, forcing the array to scratch (10+ GB spill traffic, 5x
// regression). Full static unroll keeps them in VGPRs.

// ---------------------------------------------------------------------------
// Kernel 1: symmetrize A in place (tril + tril^T + diag).
// ---------------------------------------------------------------------------
__global__ __launch_bounds__(256) void symmetrize_kernel(float* __restrict__ A) {
    const int idx = blockIdx.x * 256 + threadIdx.x;   // 128*4096 total
    const int r   = (idx >> 6) & 63;
    const int col = idx & 63;
    if (col > r) A[idx] = A[(idx & ~4095) | (col << 6) | r];
}

// ---------------------------------------------------------------------------
// Kernel 2a: Householder tridiagonalization + Sturm bisection.
// ONE WAVE per 64-thread block (1-wave workgroups reach ~15 wg/CU residency
// vs 2 blocks/CU for the 4-wave version -- measured round 1 vs rounds 0/5).
// Barrier-free: all LDS traffic is intra-wave; wave_sync() (lgkmcnt +
// sched_barrier) replaces __syncthreads, so the per-step cost loses both the
// s_barrier wave-coupling and the vmcnt(0) store drains (round-5 counters:
// 6800 cyc/step, ~95% latency). Reflector archive -> rows 0..61 of M in
// global (dead until eigvec overwrites); d -> row 62, e -> row 63,
// raw lambda -> coefs.
// ---------------------------------------------------------------------------
__global__ __launch_bounds__(64) void tridiag_kernel(float* __restrict__ X,
                                                     float* __restrict__ P,
                                                     float* __restrict__ coefs) {
    __shared__ __align__(16) float scr[64];    // column dump
    __shared__ __align__(16) float vrow[64];   // reflector v
    __shared__ __align__(16) float urow[64];   // rank-2 vector u
    __shared__ __align__(8)  v2f  DE[64];      // (d_i, e_i)
    const int lane = threadIdx.x;
    const int b    = blockIdx.x;
    float* M = (b < N_X) ? (X + (size_t)b * MAT)
                         : (P + (size_t)(b - N_X) * MAT);

    // ---- load column `lane`; track own diagonal element incrementally ----
    float wcol[64];
    float dg = 0.f;
    #pragma unroll
    for (int i = 0; i < 64; ++i) {
        wcol[i] = M[i * ND + lane];
        if (i == lane) dg = wcol[i];
    }
    float ereg = 0.f;

    // ---- Phase 1: Householder tridiagonalization, steps k = 0..61 ----
    #pragma unroll 1
    for (int k = 0; k < 62; ++k) {
        // lane k dumps its current column to LDS
        if (lane == k) {
            #pragma unroll
            for (int j = 0; j < 16; ++j)
                *(float4*)(&scr[4 * j]) =
                    make_float4(wcol[4*j], wcol[4*j+1], wcol[4*j+2], wcol[4*j+3]);
        }
        wave_sync();

        const float xj = scr[lane];           // stride-1, conflict-free
        const float x0 = scr[k + 1];          // broadcast
        const float nx2 = wsum((lane > k) ? xj * xj : 0.f);
        const float normx = sqrtf(nx2);
        const float alpha = -copysignf(normx, x0);
        const float vn2   = 2.f * (nx2 - alpha * x0);
        const bool  ok    = (nx2 > 1e-40f);
        const float rvn   = ok ? rsqrtf(vn2) : 0.f;
        float vj = 0.f;
        if (lane == k + 1)      vj = (x0 - alpha) * rvn;
        else if (lane > k)      vj = xj * rvn;
        vrow[lane] = vj;
        M[k * ND + lane] = vj;                // archive row: fire-and-forget,
                                              // never drained in this loop
        if (lane == k) ereg = alpha;          // e_k
        wave_sync();

        // read v into registers (broadcast b128 reads, FULL unroll)
        v2f vv[32];
        {
            const float4* vp = (const float4*)(&vrow[0]);
            #pragma unroll
            for (int j = 0; j < 16; ++j) {
                const float4 q = vp[j];
                vv[2*j]   = v2f{q.x, q.y};
                vv[2*j+1] = v2f{q.z, q.w};
            }
        }
        // w_j = 2 * (col_j . v)   (local dot)
        v2f acc = {0.f, 0.f};
        #pragma unroll
        for (int j = 0; j < 32; ++j)
            acc = vfma(v2f{wcol[2*j], wcol[2*j+1]}, vv[j], acc);
        const float wj = 2.f * (acc.x + acc.y);
        const float K  = wsum(vj * wj);
        const float uj = wj - K * vj;
        urow[lane] = uj;
        wave_sync();

        // read u, rank-2 update: col_j -= v*u_j + u*v_j   (FULL unroll)
        {
            const float4* up = (const float4*)(&urow[0]);
            const v2f vjv = {vj, vj}, ujv = {uj, uj};
            #pragma unroll
            for (int j = 0; j < 16; ++j) {
                const float4 q = up[j];
                v2f u0 = {q.x, q.y}, u1 = {q.z, q.w};
                v2f w0 = {wcol[4*j],   wcol[4*j+1]};
                v2f w1 = {wcol[4*j+2], wcol[4*j+3]};
                w0 = vfma(-vv[2*j],   ujv, vfma(-u0, vjv, w0));
                w1 = vfma(-vv[2*j+1], ujv, vfma(-u1, vjv, w1));
                wcol[4*j]   = w0.x; wcol[4*j+1] = w0.y;
                wcol[4*j+2] = w1.x; wcol[4*j+3] = w1.y;
            }
        }
        dg -= 2.f * uj * vj;
    }

    if (lane == 62) ereg = wcol[63];          // e_62 = A[63][62] (frozen)
    DE[lane] = v2f{dg, ereg};                 // (d_lane, e_lane)
    wave_sync();

    // ---- Phase 2: Gershgorin bounds + Sturm bisection (lane k -> lam_k) ----
    float glo = 1e30f, ghi = -1e30f;
    {
        float eprev = 0.f;
        #pragma unroll
        for (int i = 0; i < 64; ++i) {
            const v2f t = DE[i];
            const float e = (i < 63) ? fabsf(t.y) : 0.f;
            const float r = e + eprev;
            glo = fminf(glo, t.x - r);
            ghi = fmaxf(ghi, t.x + r);
            eprev = e;
        }
    }
    float lo = glo, hi = ghi;
    #pragma unroll 1
    for (int it = 0; it < BISECT_ITERS; ++it) {
        const float mid = 0.5f * (lo + hi);
        int cnt = 0;
        float p = 1.f, eprev = 0.f;
        #pragma unroll
        for (int i = 0; i < 64; ++i) {
            const v2f t = DE[i];
            const float num = eprev * eprev;
            p = (t.x - mid) - num * frcp(p);
            p = guard_piv(p);
            cnt += (p < 0.f) ? 1 : 0;
            eprev = t.y;
        }
        if (cnt <= lane) lo = mid; else hi = mid;
    }
    const float lam = 0.5f * (lo + hi);

    // ---- hand off to eigvec_kernel: d -> row 62, e -> row 63, raw lam ----
    M[62 * ND + lane] = dg;
    M[63 * ND + lane] = ereg;
    coefs[(size_t)b * ND + lane] = lam;
}

// ---------------------------------------------------------------------------
// Kernel 2b: inverse iteration + back-transform + store. 4 waves/block, one
// matrix per wave. Own kernel so the Thomas-solve register floor
// (rden[64]+y[64] ~ 150 live) can't interact with phase-1 scheduling.
// ALL array-indexing loops fully unrolled. Phase 4 prefetches the next
// reflector row (global load issued before the compute) so the L2 latency
// hides under the 32 FMAs.
// ---------------------------------------------------------------------------
__global__ __launch_bounds__(256) void eigvec_kernel(float* __restrict__ X,
                                                     float* __restrict__ P,
                                                     float* __restrict__ coefs) {
    __shared__ __align__(8)  v2f  DEb[NWAVE][64];      // (d_i, e_i)
    __shared__ __align__(16) float vrowb[NWAVE][64];   // reflector row stage
    const int wid  = threadIdx.x >> 6;
    const int lane = threadIdx.x & 63;
    const int b    = blockIdx.x * NWAVE + wid;
    float* M = (b < N_X) ? (X + (size_t)b * MAT)
                         : (P + (size_t)(b - N_X) * MAT);
    v2f*   DE   = DEb[wid];
    float* vrow = vrowb[wid];

    const float dg   = M[62 * ND + lane];
    const float ereg = M[63 * ND + lane];
    const float lam  = coefs[(size_t)b * ND + lane];
    DE[lane] = v2f{dg, ereg};
    __syncthreads();

    // ---- Phase 3: inverse iteration, tiny-pivot Thomas, 2 solves ----
    float rden[64], y[64];
    {
        // factor (reused across solves) + solve 1 with pseudo-random rhs
        float eprev;
        {
            const v2f t0 = DE[0];
            rden[0] = frcp(guard_piv(t0.x - lam));
            eprev = t0.y;
            y[0] = 0.7548f;
        }
        #pragma unroll
        for (int i = 1; i < 64; ++i) {
            const v2f ti = DE[i];
            const float m = eprev * rden[i-1];
            rden[i] = frcp(guard_piv((ti.x - lam) - m * eprev));
            const float bi = (float)(((unsigned)(i * 2654435761u)
                               ^ (unsigned)((lane + 1) * 40503u)) & 0xFFFFu)
                               * 3.0517578e-05f - 0.5f;
            y[i] = bi - m * y[i-1];
            eprev = ti.y;
        }
        y[63] *= rden[63];
        #pragma unroll
        for (int i = 62; i >= 0; --i)
            y[i] = (y[i] - DE[i].y * y[i+1]) * rden[i];

        // normalize, then solve 2 in place
        float n2 = 0.f;
        #pragma unroll
        for (int i = 0; i < 64; ++i) n2 = fmaf(y[i], y[i], n2);
        const float rn = rsqrtf(fmaxf(n2, 1e-30f));
        y[0] *= rn;
        eprev = DE[0].y;
        #pragma unroll
        for (int i = 1; i < 64; ++i) {
            const float m = eprev * rden[i-1];
            y[i] = y[i] * rn - m * y[i-1];
            eprev = DE[i].y;
        }
        y[63] *= rden[63];
        #pragma unroll
        for (int i = 62; i >= 0; --i)
            y[i] = (y[i] - DE[i].y * y[i+1]) * rden[i];
        n2 = 0.f;
        #pragma unroll
        for (int i = 0; i < 64; ++i) n2 = fmaf(y[i], y[i], n2);
        const float rn2 = rsqrtf(fmaxf(n2, 1e-30f));
        #pragma unroll
        for (int i = 0; i < 64; ++i) y[i] *= rn2;
    }

    // ---- Phase 3b: Gram-Schmidt vs lower neighbor when lambdas nearly
    // equal. Shuffle the neighbor column twice (lockstep: second pass reads
    // pre-update values) -- no yp[64] copy. ----
    {
        const float lamprev = __shfl(lam, lane - 1);
        const bool doGS = (lane > 0) && ((lam - lamprev) < 1e-3f * fabsf(lam));
        float dot = 0.f;
        #pragma unroll
        for (int i = 0; i < 64; ++i)
            dot = fmaf(y[i], __shfl(y[i], lane - 1), dot);
        const float s = doGS ? dot : 0.f;
        float n2 = 0.f;
        #pragma unroll
        for (int i = 0; i < 64; ++i) {
            const float ypi = __shfl(y[i], lane - 1);
            y[i] = fmaf(-s, ypi, y[i]);
            n2 = fmaf(y[i], y[i], n2);
        }
        const float rn = rsqrtf(fmaxf(n2, 1e-30f));
        #pragma unroll
        for (int i = 0; i < 64; ++i) y[i] *= rn;
    }

    // ---- Phase 4: back-transform y <- Q y = H_0(...(H_61 y)). Reflector
    // row staged through the wave's LDS row; the NEXT row's coalesced global
    // load is issued before the compute so its latency hides under the 32
    // FMAs. FULL unroll keeps y[] in registers. Fences are wave-local. ----
    float gv = M[61 * ND + lane];             // prefetch row 61
    #pragma unroll 1
    for (int k = 61; k >= 0; --k) {
        vrow[lane] = gv;                      // compiler inserts vmcnt wait
        asm volatile("s_waitcnt lgkmcnt(0)" ::: "memory");
        if (k > 0) gv = M[(k - 1) * ND + lane];   // issue next-row load early
        __builtin_amdgcn_sched_barrier(0);
        const float4* vp = (const float4*)(&vrow[0]);
        v2f acc = {0.f, 0.f};
        #pragma unroll
        for (int j = 0; j < 16; ++j) {
            const float4 q = vp[j];
            acc = vfma(v2f{y[4*j],   y[4*j+1]}, v2f{q.x, q.y}, acc);
            acc = vfma(v2f{y[4*j+2], y[4*j+3]}, v2f{q.z, q.w}, acc);
        }
        const float s2 = 2.f * (acc.x + acc.y);
        #pragma unroll
        for (int j = 0; j < 16; ++j) {
            const float4 q = vp[j];
            y[4*j+0] = fmaf(-s2, q.x, y[4*j+0]);
            y[4*j+1] = fmaf(-s2, q.y, y[4*j+1]);
            y[4*j+2] = fmaf(-s2, q.z, y[4*j+2]);
            y[4*j+3] = fmaf(-s2, q.w, y[4*j+3]);
        }
        // per-wave in-order DS keeps next iter's ds_write after these reads
    }

    // ---- Phase 5: store eigvec column + log(lambda) ----
    #pragma unroll
    for (int i = 0; i < 64; ++i) M[i * ND + lane] = y[i];
    coefs[(size_t)b * ND + lane] = logf(fmaxf(lam, 1e-12f));
}

// ---------------------------------------------------------------------------
// Kernel 3: recompose logm[i][j] = sum_k coef_k * W[i][k] * W[j][k].
// One matrix per 256-thread block, in place over W.
// ---------------------------------------------------------------------------
__global__ __launch_bounds__(256, 4) void recompose_kernel(float* __restrict__ X,
                                                           float* __restrict__ P,
                                                           const float* __restrict__ coefs) {
    __shared__ __align__(16) float WR[ND][68];   // WR[k][i] = W[i][k]
    __shared__ float Cf[ND];
    const int b = blockIdx.x;
    float* M = (b < N_X) ? (X + (size_t)b * MAT)
                         : (P + (size_t)(b - N_X) * MAT);
    const int tid = threadIdx.x;

    { // load + transpose: thread -> row r, 16-col segment q
        const int r = tid >> 2, q = (tid & 3) * 16;
        const float4 v0 = *(const float4*)(&M[r * ND + q + 0]);
        const float4 v1 = *(const float4*)(&M[r * ND + q + 4]);
        const float4 v2 = *(const float4*)(&M[r * ND + q + 8]);
        const float4 v3 = *(const float4*)(&M[r * ND + q + 12]);
        WR[q+ 0][r]=v0.x; WR[q+ 1][r]=v0.y; WR[q+ 2][r]=v0.z; WR[q+ 3][r]=v0.w;
        WR[q+ 4][r]=v1.x; WR[q+ 5][r]=v1.y; WR[q+ 6][r]=v1.z; WR[q+ 7][r]=v1.w;
        WR[q+ 8][r]=v2.x; WR[q+ 9][r]=v2.y; WR[q+10][r]=v2.z; WR[q+11][r]=v2.w;
        WR[q+12][r]=v3.x; WR[q+13][r]=v3.y; WR[q+14][r]=v3.z; WR[q+15][r]=v3.w;
    }
    if (tid < ND) Cf[tid] = coefs[(size_t)b * ND + tid];
    __syncthreads();

    const int tx = tid & 15, ty = tid >> 4;   // 4x4 output block per thread

    v2f a00={0,0},a01={0,0},a10={0,0},a11={0,0},
        a20={0,0},a21={0,0},a30={0,0},a31={0,0};

    #pragma unroll 4
    for (int k = 0; k < ND; ++k) {
        const v2f* row = (const v2f*)(&WR[k][0]);
        const float sk = Cf[k];
        const v2f skv = {sk, sk};
        const v2f aA = row[ty*2], aB = row[ty*2 + 1];
        const v2f b0 = row[tx*2] * skv, b1 = row[tx*2 + 1] * skv;
        const v2f ax0 = {aA.x, aA.x}, ax1 = {aA.y, aA.y};
        const v2f ax2 = {aB.x, aB.x}, ax3 = {aB.y, aB.y};
        a00 = vfma(ax0, b0, a00);  a01 = vfma(ax0, b1, a01);
        a10 = vfma(ax1, b0, a10);  a11 = vfma(ax1, b1, a11);
        a20 = vfma(ax2, b0, a20);  a21 = vfma(ax2, b1, a21);
        a30 = vfma(ax3, b0, a30);  a31 = vfma(ax3, b1, a31);
    }

    const int i0 = ty * 4, j0 = tx * 4;
    *(float4*)(&M[(size_t)(i0+0)*ND + j0]) = make_float4(a00.x,a00.y,a01.x,a01.y);
    *(float4*)(&M[(size_t)(i0+1)*ND + j0]) = make_float4(a10.x,a10.y,a11.x,a11.y);
    *(float4*)(&M[(size_t)(i0+2)*ND + j0]) = make_float4(a20.x,a20.y,a21.x,a21.y);
    *(float4*)(&M[(size_t)(i0+3)*ND + j0]) = make_float4(a30.x,a30.y,a31.x,a31.y);
}

// ---------------------------------------------------------------------------
// Kernel 4: off[c] = <logm(P_c), Asym_c>   (one wave per class)
// ---------------------------------------------------------------------------
__global__ __launch_bounds__(64) void off_kernel(const float* __restrict__ LP,
                                                 const float* __restrict__ AS,
                                                 float* __restrict__ off) {
    const int c = blockIdx.x, lane = threadIdx.x;
    const float* lp = LP + (size_t)c * MAT;
    const float* as = AS + (size_t)c * MAT;
    float t = 0.f;
    #pragma unroll 8
    for (int i = 0; i < ND; ++i)
        t = fmaf(lp[i * ND + lane], as[i * ND + lane], t);
    #pragma unroll
    for (int m = 32; m >= 1; m >>= 1) t += __shfl_xor(t, m);
    if (lane == 0) off[c] = t;
}

// ---------------------------------------------------------------------------
// Kernel 5: logits GEMM  out[n,c] = sum_k LX[n,k]*AS[c,k] - off[c]
// ---------------------------------------------------------------------------
__global__ __launch_bounds__(256) void logits_kernel(const float* __restrict__ LX,
                                                     const float* __restrict__ AS,
                                                     const float* __restrict__ off,
                                                     float* __restrict__ out) {
    __shared__ __align__(16) float LXs[32][132];
    __shared__ __align__(16) float ASs[32][132];
    const int tid = threadIdx.x;
    const int tx = tid & 15, ty = tid >> 4;
    const int nbase = blockIdx.x * 128;

    float offv[8];
    #pragma unroll
    for (int j = 0; j < 8; ++j) offv[j] = off[tx * 8 + j];

    float acc[8][8];
    #pragma unroll
    for (int i = 0; i < 8; ++i)
        #pragma unroll
        for (int j = 0; j < 8; ++j) acc[i][j] = 0.f;

    #pragma unroll 1
    for (int kc = 0; kc < MAT; kc += 32) {
        #pragma unroll
        for (int u = 0; u < 4; ++u) {
            const int f  = u * 256 + tid;
            const int r  = f >> 3;
            const int c4 = (f & 7) * 4;
            const float4 v = *(const float4*)(&LX[(size_t)(nbase + r) * MAT + kc + c4]);
            LXs[c4+0][r] = v.x; LXs[c4+1][r] = v.y; LXs[c4+2][r] = v.z; LXs[c4+3][r] = v.w;
            const float4 g = *(const float4*)(&AS[(size_t)r * MAT + kc + c4]);
            ASs[c4+0][r] = g.x; ASs[c4+1][r] = g.y; ASs[c4+2][r] = g.z; ASs[c4+3][r] = g.w;
        }
        __syncthreads();
        #pragma unroll 4
        for (int kk = 0; kk < 32; ++kk) {
            const float4 a0 = *(const float4*)(&LXs[kk][ty * 8]);
            const float4 a1 = *(const float4*)(&LXs[kk][ty * 8 + 4]);
            const float4 b0 = *(const float4*)(&ASs[kk][tx * 8]);
            const float4 b1 = *(const float4*)(&ASs[kk][tx * 8 + 4]);
            const float av[8] = {a0.x,a0.y,a0.z,a0.w,a1.x,a1.y,a1.z,a1.w};
            const float bv[8] = {b0.x,b0.y,b0.z,b0.w,b1.x,b1.y,b1.z,b1.w};
            #pragma unroll
            for (int i = 0; i < 8; ++i)
                #pragma unroll
                for (int j = 0; j < 8; ++j)
                    acc[i][j] = fmaf(av[i], bv[j], acc[i][j]);
        }
        __syncthreads();
    }

    #pragma unroll
    for (int i = 0; i < 8; ++i) {
        const int n = nbase + ty * 8 + i;
        const float4 o0 = make_float4(acc[i][0]-offv[0], acc[i][1]-offv[1],
                                      acc[i][2]-offv[2], acc[i][3]-offv[3]);
        const float4 o1 = make_float4(acc[i][4]-offv[4], acc[i][5]-offv[5],
                                      acc[i][6]-offv[6], acc[i][7]-offv[7]);
        *(float4*)(&out[(size_t)n * 128 + tx * 8])     = o0;
        *(float4*)(&out[(size_t)n * 128 + tx * 8 + 4]) = o1;
    }
}

// ---------------------------------------------------------------------------
extern "C" void kernel_launch(void* const* d_in, const int* in_sizes, int n_in,
                              void* d_out, int out_size, void* d_ws, size_t ws_size,
                              hipStream_t stream) {
    float* X   = (float*)d_in[0];
    float* P   = (float*)d_in[1];
    float* A   = (float*)d_in[2];
    float* out = (float*)d_out;
    float* off = (float*)d_ws;            // 128 floats of scratch
    // coef scratch (32896*64 floats = 8.4 MB) lives in d_out (16.8 MB):
    // raw lam written by tridiag, read+overwritten (log) by eigvec, consumed
    // by recompose, then logits overwrites all of d_out last.
    float* coefs = (float*)d_out;

    hipLaunchKernelGGL(symmetrize_kernel, dim3((N_P * MAT) / 256),   dim3(256), 0, stream, A);
    hipLaunchKernelGGL(tridiag_kernel,    dim3(N_X + N_P),           dim3(64),  0, stream, X, P, coefs);
    hipLaunchKernelGGL(eigvec_kernel,     dim3((N_X + N_P) / NWAVE), dim3(256), 0, stream, X, P, coefs);
    hipLaunchKernelGGL(recompose_kernel,  dim3(N_X + N_P),           dim3(256), 0, stream, X, P, coefs);
    hipLaunchKernelGGL(off_kernel,        dim3(N_P),                 dim3(64),  0, stream, P, A, off);
    hipLaunchKernelGGL(logits_kernel,     dim3(N_X / 128),           dim3(256), 0, stream, X, A, off, out);
}